// Round 4
// baseline (126.961 us; speedup 1.0000x reference)
//
#include <hip/hip_runtime.h>
#include <math.h>

#define NROWS 8192
#define NC 10
#define TJ 128
#define LOG2E_F 1.4426950408889634f

typedef float f32x2 __attribute__((ext_vector_type(2)));

#if __has_builtin(__builtin_amdgcn_exp2f)
#define EXP2F(x) __builtin_amdgcn_exp2f(x)
#else
#define EXP2F(x) exp2f(x)
#endif

// ws layout (floats):
//   P    : [N][12]  = {f0..f9, B2h, B2h|label}  B2h = -B2/2   (12N)
//   L10  : [N][10]  = 10*log2(f+1e-45)                        (10N)
//   psum : [N]                                                (N)
//   part : [nchunk][11][N] = {acc0..acc9, den} SoA            (11*nchunk*N)

__global__ __launch_bounds__(256) void kde_prep(const float* __restrict__ logits,
                                                const int* __restrict__ labels,
                                                float* __restrict__ P,
                                                float* __restrict__ L10) {
    int i = blockIdx.x * 256 + threadIdx.x;
    if (i >= NROWS) return;
    float l[NC];
#pragma unroll
    for (int c = 0; c < NC; ++c) l[c] = logits[i * NC + c];
    float m = l[0];
#pragma unroll
    for (int c = 1; c < NC; ++c) m = fmaxf(m, l[c]);
    float e[NC];
    float sum = 0.f;
#pragma unroll
    for (int c = 0; c < NC; ++c) { e[c] = expf(l[c] - m); sum += e[c]; }
    float lg = 0.f;
#pragma unroll
    for (int c = 0; c < NC; ++c) {
        float f = e[c] / sum;
        P[i * 12 + c] = f;
        L10[i * NC + c] = 10.f * log2f(f + 1e-45f);
        lg += lgammaf(fmaf(10.f, f, 1.f));
    }
    // sum(alphas) == 1/h + C == 20 exactly -> lgamma(sum) is a constant.
    // Store -B2/2 twice; the pair seeds the packed-fma chain (horizontal sum
    // adds both halves -> -B2). Label lives in slot 11's low 4 mantissa bits
    // (perturbs exponent by ~3e-5; bit-consistent with finish1).
    float b2 = (lg - lgammaf(20.0f)) * LOG2E_F;
    float b2h = -0.5f * b2;
    P[i * 12 + 10] = b2h;
    P[i * 12 + 11] = __int_as_float((__float_as_int(b2h) & ~15) | (labels[i] & 15));
}

// exponent = dot(la, f_j) - B2_j, packed form; init pair {c2.z, c2.w} = {B2h, B2h'}
__device__ __forceinline__ float kern_exponent(const f32x2 la[5],
                                               float4 c0, float4 c1, float4 c2) {
    f32x2 q0 = {c0.x, c0.y}, q1 = {c0.z, c0.w};
    f32x2 q2 = {c1.x, c1.y}, q3 = {c1.z, c1.w};
    f32x2 q4 = {c2.x, c2.y};
    f32x2 init = {c2.z, c2.w};
    f32x2 cA = __builtin_elementwise_fma(la[0], q0,
               __builtin_elementwise_fma(la[2], q2, la[4] * q4));
    f32x2 cB = __builtin_elementwise_fma(la[1], q1,
               __builtin_elementwise_fma(la[3], q3, init));
    f32x2 cS = cA + cB;
    return cS.x + cS.y;
}

__global__ __launch_bounds__(256) void kde_main(const float* __restrict__ P,
                                                const float* __restrict__ L10,
                                                float* __restrict__ part,
                                                int nchunk) {
    __shared__ float sP[(TJ + 1) * 12];   // +1 row pad for prefetch overshoot
    const int tid = threadIdx.x;
    const int i0 = blockIdx.x * 1024 + tid;   // 4 i-rows: i0 + r*256

    f32x2 la[4][5];
#pragma unroll
    for (int r = 0; r < 4; ++r)
#pragma unroll
        for (int c = 0; c < 5; ++c)
            la[r][c] = *(const f32x2*)&L10[(i0 + r * 256) * NC + 2 * c];

    float acc[4][NC];
    float den[4] = {0.f, 0.f, 0.f, 0.f};
#pragma unroll
    for (int r = 0; r < 4; ++r)
#pragma unroll
        for (int c = 0; c < NC; ++c) acc[r][c] = 0.f;

    const int jsz = NROWS / nchunk;
    const int jbeg = blockIdx.y * jsz;
    for (int js = jbeg; js < jbeg + jsz; js += TJ) {
        __syncthreads();
        const float4* gsrc = (const float4*)(P + (size_t)js * 12);
        float4* ldst = (float4*)sP;
        ldst[tid] = gsrc[tid];                       // 384 float4 = 128 rows
        if (tid < TJ * 3 - 256) ldst[256 + tid] = gsrc[256 + tid];
        __syncthreads();

        float4 n0 = *(const float4*)&sP[0];
        float4 n1 = *(const float4*)&sP[4];
        float4 n2 = *(const float4*)&sP[8];
#pragma unroll 4
        for (int jj = 0; jj < TJ; ++jj) {
            float4 c0 = n0, c1 = n1, c2 = n2;
            const float* nr = &sP[(jj + 1) * 12];    // prefetch next row
            n0 = *(const float4*)(nr);
            n1 = *(const float4*)(nr + 4);
            n2 = *(const float4*)(nr + 8);
            int lab = __builtin_amdgcn_readfirstlane(__float_as_int(c2.w)) & 15;
            float k0 = EXP2F(kern_exponent(la[0], c0, c1, c2));
            float k1 = EXP2F(kern_exponent(la[1], c0, c1, c2));
            float k2 = EXP2F(kern_exponent(la[2], c0, c1, c2));
            float k3 = EXP2F(kern_exponent(la[3], c0, c1, c2));
            den[0] += k0; den[1] += k1; den[2] += k2; den[3] += k3;
            switch (lab) {   // block-uniform scalar branch
#define CASE(c) case c: acc[0][c]+=k0; acc[1][c]+=k1; acc[2][c]+=k2; acc[3][c]+=k3; break;
                CASE(0) CASE(1) CASE(2) CASE(3) CASE(4)
                CASE(5) CASE(6) CASE(7) CASE(8) CASE(9)
#undef CASE
            }
        }
    }

    // SoA: part[(chunk*11 + c)*N + i] — coalesced
    float* pbase = part + (size_t)blockIdx.y * 11 * NROWS;
#pragma unroll
    for (int r = 0; r < 4; ++r) {
        float* pb = pbase + (i0 + r * 256);
#pragma unroll
        for (int c = 0; c < NC; ++c) pb[(size_t)c * NROWS] = acc[r][c];
        pb[(size_t)10 * NROWS] = den[r];
    }
}

__global__ __launch_bounds__(256) void kde_finish1(const float* __restrict__ part,
                                                   const float* __restrict__ P,
                                                   const float* __restrict__ L10,
                                                   float* __restrict__ psum,
                                                   int nchunk) {
    int i = blockIdx.x * 256 + threadIdx.x;
    float acc[NC];
    float den = 0.f;
#pragma unroll
    for (int c = 0; c < NC; ++c) acc[c] = 0.f;
    for (int ch = 0; ch < nchunk; ++ch) {
        const float* pb = part + (size_t)ch * 11 * NROWS + i;
#pragma unroll
        for (int c = 0; c < NC; ++c) acc[c] += pb[(size_t)c * NROWS];
        den += pb[(size_t)10 * NROWS];
    }

    // subtract self-kernel kern[i][i] (leave-one-out), bit-identical eval
    f32x2 la[5];
#pragma unroll
    for (int c = 0; c < 5; ++c)
        la[c] = *(const f32x2*)&L10[i * NC + 2 * c];
    float4 v0 = *(const float4*)&P[i * 12];
    float4 v1 = *(const float4*)&P[i * 12 + 4];
    float4 v2 = *(const float4*)&P[i * 12 + 8];
    float self = EXP2F(kern_exponent(la, v0, v1, v2));
    int lab = __float_as_int(v2.w) & 15;
    den -= self;
    acc[lab] -= self;

    den = fmaxf(den, 1e-10f);   // clip(den, EPS_DEN, None)
    float per = 0.f;
    const float* f = &P[i * 12];
#pragma unroll
    for (int c = 0; c < NC; ++c) per += fabsf(acc[c] / den - f[c]);
    psum[i] = per;
}

__global__ __launch_bounds__(256) void kde_finish2(const float* __restrict__ psum,
                                                   float* __restrict__ out) {
    __shared__ float red[256];
    int t = threadIdx.x;
    float s = 0.f;
    for (int k = t; k < NROWS; k += 256) s += psum[k];
    red[t] = s;
    __syncthreads();
    for (int off = 128; off > 0; off >>= 1) {
        if (t < off) red[t] += red[t + off];
        __syncthreads();
    }
    if (t == 0) out[0] = red[0] * (1.0f / NROWS);
}

extern "C" void kernel_launch(void* const* d_in, const int* in_sizes, int n_in,
                              void* d_out, int out_size, void* d_ws, size_t ws_size,
                              hipStream_t stream) {
    const float* logits = (const float*)d_in[0];
    const int* labels = (const int*)d_in[1];
    float* out = (float*)d_out;
    float* ws = (float*)d_ws;

    float* P = ws;                        // 12N floats
    float* L10 = ws + 12 * NROWS;         // 10N floats
    float* psum = ws + 22 * NROWS;        // N floats
    float* part = ws + 23 * NROWS;        // nchunk * 11N floats

    int nchunk = 64;                      // 8 i-tiles x 64 chunks = 512 blocks
    while (nchunk > 1 &&
           (size_t)(23 + 11 * nchunk) * NROWS * sizeof(float) > ws_size)
        nchunk >>= 1;

    kde_prep<<<dim3(NROWS / 256), dim3(256), 0, stream>>>(logits, labels, P, L10);
    kde_main<<<dim3(NROWS / 1024, nchunk), dim3(256), 0, stream>>>(P, L10, part, nchunk);
    kde_finish1<<<dim3(NROWS / 256), dim3(256), 0, stream>>>(part, P, L10, psum, nchunk);
    kde_finish2<<<dim3(1), dim3(256), 0, stream>>>(psum, out);
}